// Round 9
// baseline (9146.489 us; speedup 1.0000x reference)
//
#include <hip/hip_runtime.h>
#include <hip/hip_bf16.h>

// LSTM T=512 B=256 NP=34 H=512 NT=16.
// R9 = R8 barrier-free dataflow + one-line fix: consumer fragment base stride
// is m*128 u64 (512 bf16 per batch row), not m*64. R8's wrong stride made
// consumers read wrong-batch h (absmax 2.4e-3); protocol itself was sound.
// 16 groups (16 batches) x 16 blocks (32 h-cols, all 4 gates), 1 block/CU.
// - Swapped-operand MFMA (R7-validated): A = W rows (LDS-resident, pr-mapping),
//   B = h batches => lane's acc regs 0..3 = gates i,f,g,o of one (batch,col).
// - NO LDS h-staging, NO per-step barriers: B-fragment of K-step s is 16
//   contiguous bytes of h written by one store instruction of producer block
//   s / wave ko. Lane issues 32 relaxed agent-scope u64 loads up front,
//   validates per-fragment vs sentinel in K-order (retrying stragglers),
//   MFMAs directly from registers.
// - Sentinel protocol: hs pre-memset 0xAAAAAAAA; every dword written exactly
//   once; the successful poll IS the data load. Global per-wave retry budget
//   bounds pathological stalls (wrong-answer, never timeout).
#define TT 512
#define BT 256
#define NP 34
#define HH 512
#define SENT 0xAAAAAAAAu

typedef short bf16x8 __attribute__((ext_vector_type(8)));
typedef float f32x4 __attribute__((ext_vector_type(4)));

static __device__ __forceinline__ unsigned short f2bf(float x) {
  unsigned int u = __float_as_uint(x);
  unsigned int r = (u + 0x7fffu + ((u >> 16) & 1u)) >> 16;
  return (unsigned short)r;
}

#define OKU64(x) (((unsigned int)(x) != SENT) && ((unsigned int)((x) >> 32) != SENT))

// LDS (147456 B dynamic): Wl bf16 [128 rows][576], chunk swizzle phys = c ^ (pr&7)
__global__ void __launch_bounds__(256, 1) lstm_coop(
    const float* __restrict__ Whh, const float* __restrict__ Wih,
    const float* __restrict__ bih, const float* __restrict__ bhh,
    const unsigned short* __restrict__ Ax,  // [T][256][64] bf16 bits
    unsigned short* hs)                     // [T][256][512] bf16 bits, pre-SENT
{
  extern __shared__ char smem[];
  unsigned short* Wl = (unsigned short*)smem;

  const int tid = threadIdx.x;
  const int g = blockIdx.x & 15;   // group
  const int n = blockIdx.x >> 4;   // block-in-group -> h-cols [n*32, n*32+32)
  const int bbase = g * 16;        // batch base

  // ---- init resident W slice: pr = w*32 + e*16 + (4*jj+q) -> (gate q, col w*8+2jj+e)
  for (int idx = tid; idx < 128 * 576; idx += 256) {
    int pr = idx / 576, k = idx - pr * 576;
    int w_ = pr >> 5, e = (pr >> 4) & 1, mr = pr & 15;
    int jloc = w_ * 8 + ((mr >> 2) << 1) + e;           // col in [0,32)
    int grow = (mr & 3) * 512 + n * 32 + jloc;          // gate (mr&3), global col
    float v = 0.f;
    if (k < 512) v = Whh[(size_t)grow * 512 + k];
    else if (k < 546) v = Wih[grow * 34 + (k - 512)];
    int c = k >> 3, within = k & 7;
    Wl[pr * 576 + ((c ^ (pr & 7)) << 3) + within] = f2bf(v);
  }

  const int lane = tid & 63;
  const int w = tid >> 6;
  const int m = lane & 15;   // batch (B col, A row-low)
  const int ko = lane >> 4;
  const int rA = 32 * w + m;        // A rows e=0 tile; rB = e=1 tile
  const int rB = rA + 16;           // (rA&7 == rB&7 == m&7)
  const int pM = m & 7;
  const int jc = w * 8 + (ko << 1); // local col of acc0; acc1 -> jc+1
  f32x4 biasA, biasB;
#pragma unroll
  for (int p = 0; p < 4; ++p) {
    int gr = p * 512 + n * 32 + jc;
    biasA[p] = bih[gr] + bhh[gr];
    biasB[p] = bih[gr + 1] + bhh[gr + 1];
  }
  float c0s = 0.f, c1s = 0.f;  // cell state for (batch m, cols jc, jc+1)
  int budget = 1 << 16;        // global retry budget (bounds worst-case stall)

  __syncthreads();  // Wl ready — the ONLY barrier; recurrence is barrier-free

  for (int t = 0; t < TT; ++t) {
    // x fragments (independent of h)
    const unsigned short* xbase = Ax + ((size_t)t * BT + bbase + m) * 64;
    bf16x8 xv0 = *(const bf16x8*)(xbase + (ko << 3));
    bf16x8 xv1 = *(const bf16x8*)(xbase + 32 + (ko << 3));

    f32x4 acc0 = biasA, acc1 = biasB;

    if (t > 0) {
      // this lane's 16 B-fragments of h(t-1): batch row = 128 u64; fragment s
      // = u64 pair at col offset 8*s + 2*ko  [R8 bug was m*64 here]
      const unsigned long long* hb64 =
          (const unsigned long long*)(hs + ((size_t)(t - 1) * BT + bbase) * HH)
          + m * 128 + 2 * ko;
      unsigned long long fa[16], fb[16];
#pragma unroll
      for (int s = 0; s < 16; ++s) {
        fa[s] = __hip_atomic_load(hb64 + 8 * s, __ATOMIC_RELAXED, __HIP_MEMORY_SCOPE_AGENT);
        fb[s] = __hip_atomic_load(hb64 + 8 * s + 1, __ATOMIC_RELAXED, __HIP_MEMORY_SCOPE_AGENT);
      }
#pragma unroll
      for (int s = 0; s < 16; ++s) {
        // validate fragment s (4 dwords); retry stragglers (divergent, rare)
        while (!(OKU64(fa[s]) && OKU64(fb[s])) && budget > 0) {
          --budget;
          fa[s] = __hip_atomic_load(hb64 + 8 * s, __ATOMIC_RELAXED, __HIP_MEMORY_SCOPE_AGENT);
          fb[s] = __hip_atomic_load(hb64 + 8 * s + 1, __ATOMIC_RELAXED, __HIP_MEMORY_SCOPE_AGENT);
        }
        union { unsigned long long q[2]; bf16x8 v; } u;
        u.q[0] = fa[s]; u.q[1] = fb[s];
        int cc = 4 * s + ko;
        int cs = (cc ^ pM) << 3;
        bf16x8 bv0 = *(const bf16x8*)&Wl[rA * 576 + cs];
        bf16x8 bv1 = *(const bf16x8*)&Wl[rB * 576 + cs];
        acc0 = __builtin_amdgcn_mfma_f32_16x16x32_bf16(bv0, u.v, acc0, 0, 0, 0);
        acc1 = __builtin_amdgcn_mfma_f32_16x16x32_bf16(bv1, u.v, acc1, 0, 0, 0);
      }
    }
    // x tail: s=16,17 (k = 512..575 region of Wl)
#pragma unroll
    for (int s = 16; s < 18; ++s) {
      int cc = 4 * s + ko;
      int cs = (cc ^ pM) << 3;
      bf16x8 av = (s == 16) ? xv0 : xv1;
      bf16x8 bv0 = *(const bf16x8*)&Wl[rA * 576 + cs];
      bf16x8 bv1 = *(const bf16x8*)&Wl[rB * 576 + cs];
      acc0 = __builtin_amdgcn_mfma_f32_16x16x32_bf16(bv0, av, acc0, 0, 0, 0);
      acc1 = __builtin_amdgcn_mfma_f32_16x16x32_bf16(bv1, av, acc1, 0, 0, 0);
    }

    // ---- epilogue: acc regs 0..3 = gates i,f,g,o for (batch m, col jc/jc+1)
    float i0 = 1.f / (1.f + __expf(-acc0[0])), i1 = 1.f / (1.f + __expf(-acc1[0]));
    float f0 = 1.f / (1.f + __expf(-acc0[1])), f1 = 1.f / (1.f + __expf(-acc1[1]));
    float g0 = 1.f - 2.f / (1.f + __expf(2.f * acc0[2]));
    float g1 = 1.f - 2.f / (1.f + __expf(2.f * acc1[2]));
    float o0 = 1.f / (1.f + __expf(-acc0[3])), o1 = 1.f / (1.f + __expf(-acc1[3]));
    c0s = f0 * c0s + i0 * g0;
    c1s = f1 * c1s + i1 * g1;
    float h0 = o0 * (1.f - 2.f / (1.f + __expf(2.f * c0s)));
    float h1 = o1 * (1.f - 2.f / (1.f + __expf(2.f * c1s)));
    unsigned int packed = (unsigned int)f2bf(h0) | ((unsigned int)f2bf(h1) << 16);
    // direct per-lane store (agent scope, fire-and-forget; consumer validates)
    unsigned int* dst = (unsigned int*)hs +
        ((size_t)t * BT + bbase + m) * 256 + n * 16 + w * 4 + ko;
    __hip_atomic_store(dst, packed, __ATOMIC_RELAXED, __HIP_MEMORY_SCOPE_AGENT);
  }
}

// Ax[t][b][k] = bf16(points[t][b][k]) for k<34 else 0
__global__ void __launch_bounds__(256) prep_ax(const float* __restrict__ pts,
                                               unsigned short* __restrict__ Ax) {
  size_t i = (size_t)blockIdx.x * 256 + threadIdx.x;  // [0, 512*256*64)
  int k = (int)(i & 63);
  size_t tb = i >> 6;
  float v = (k < NP) ? pts[tb * NP + k] : 0.f;
  Ax[i] = f2bf(v);
}

// logits = hs @ W_lin^T + b_lin ; softmax over 16
__global__ void __launch_bounds__(256) head_kernel(const unsigned short* __restrict__ hs,
                                                   const float* __restrict__ Wlin,
                                                   const float* __restrict__ blin,
                                                   float* __restrict__ out) {
  __shared__ float wl[16 * 513];
  __shared__ float bl[16];
  __shared__ unsigned short hl[16 * 520];
  const int tid = threadIdx.x;
  for (int i = tid; i < 16 * 512; i += 256) wl[(i >> 9) * 513 + (i & 511)] = Wlin[i];
  if (tid < 16) bl[tid] = blin[tid];
  const size_t Rb = (size_t)blockIdx.x * 16;  // 16 rows of [131072][512]
  const uint4* gsrc = (const uint4*)(hs + Rb * 512);
#pragma unroll
  for (int j = 0; j < 4; ++j) {
    int e8 = tid + 256 * j;  // uint4 index, 8 bf16 each
    uint4 v = gsrc[e8];
    int r = e8 >> 6, k = (e8 & 63) << 3;
    *(uint4*)&hl[r * 520 + k] = v;
  }
  __syncthreads();
  const int r = tid >> 4, tg = tid & 15;
  float acc = bl[tg];
  const float* wp = &wl[tg * 513];
#pragma unroll 4
  for (int k8 = 0; k8 < 64; ++k8) {
    uint4 hv = *(const uint4*)&hl[r * 520 + (k8 << 3)];
    const float* w8 = wp + (k8 << 3);
    acc += __uint_as_float(hv.x << 16) * w8[0];
    acc += __uint_as_float(hv.x & 0xffff0000u) * w8[1];
    acc += __uint_as_float(hv.y << 16) * w8[2];
    acc += __uint_as_float(hv.y & 0xffff0000u) * w8[3];
    acc += __uint_as_float(hv.z << 16) * w8[4];
    acc += __uint_as_float(hv.z & 0xffff0000u) * w8[5];
    acc += __uint_as_float(hv.w << 16) * w8[6];
    acc += __uint_as_float(hv.w & 0xffff0000u) * w8[7];
  }
  float mx = acc;
#pragma unroll
  for (int d = 8; d; d >>= 1) mx = fmaxf(mx, __shfl_xor(mx, d, 16));
  float e = __expf(acc - mx);
  float sm = e;
#pragma unroll
  for (int d = 8; d; d >>= 1) sm += __shfl_xor(sm, d, 16);
  out[Rb * 16 + tid] = e / sm;
}

extern "C" void kernel_launch(void* const* d_in, const int* in_sizes, int n_in,
                              void* d_out, int out_size, void* d_ws, size_t ws_size,
                              hipStream_t stream) {
  (void)in_sizes; (void)n_in; (void)out_size; (void)ws_size;
  const float* pts  = (const float*)d_in[0];
  const float* Wih  = (const float*)d_in[1];
  const float* Whh  = (const float*)d_in[2];
  const float* bih  = (const float*)d_in[3];
  const float* bhh  = (const float*)d_in[4];
  const float* Wlin = (const float*)d_in[5];
  const float* blin = (const float*)d_in[6];
  float* out = (float*)d_out;
  char* ws = (char*)d_ws;
  // ws layout: hs 134217728 B | Ax 16777216 B
  unsigned short* hs = (unsigned short*)ws;
  unsigned short* Ax = (unsigned short*)(ws + 134217728);

  hipMemsetAsync(hs, 0xAA, 134217728, stream);   // sentinel fill (every launch)
  prep_ax<<<32768, 256, 0, stream>>>(pts, Ax);
  (void)hipFuncSetAttribute((const void*)lstm_coop,
                            hipFuncAttributeMaxDynamicSharedMemorySize, 147456);
  void* args[6];
  args[0] = (void*)&Whh; args[1] = (void*)&Wih; args[2] = (void*)&bih;
  args[3] = (void*)&bhh; args[4] = (void*)&Ax;  args[5] = (void*)&hs;
  hipLaunchCooperativeKernel((void*)lstm_coop, dim3(256), dim3(256), args, 147456, stream);
  head_kernel<<<8192, 256, 0, stream>>>(hs, Wlin, blin, out);
}